// Round 2
// baseline (874.162 us; speedup 1.0000x reference)
//
#include <hip/hip_runtime.h>
#include <math.h>

#define BB 256
#define TT 1024
#define KK 128
#define NB 16                 // batches per forward block
#define NBLK (BB / NB)        // 16 forward blocks
#define NTHR 512
#define CHUNK 4
#define NCHUNK (TT / CHUNK)   // 256
#define PSTR 136              // ushorts per P row (272 B): 16B-aligned, bank-balanced

typedef __attribute__((ext_vector_type(8))) short bf16x8;
typedef __attribute__((ext_vector_type(4))) float f32x4;

__global__ void zero_out_kernel(float* out) { out[0] = 0.0f; }

// RNE float -> bf16 bits
__device__ __forceinline__ unsigned short f2bf(float x) {
    unsigned b = __float_as_uint(x);
    return (unsigned short)((b + 0x7FFFu + ((b >> 16) & 1u)) >> 16);
}

// LGKM-only barrier: LDS is the only cross-wave dependency in the hot loop;
// global prefetch loads stay in flight across step barriers (never drain vmcnt).
#define BARSYNC() { asm volatile("s_waitcnt lgkmcnt(0)" ::: "memory"); \
                    __builtin_amdgcn_s_barrier(); \
                    asm volatile("" ::: "memory"); }

// X layout: [s][batch r][128], 16B granule g of row r stored at g ^ (r&7)
// (kills the 4-way bank conflict on the per-lane scalar X reads).
#define XI(S, R, J) (((S) * NB + (R)) * KK + ((((J) >> 2) ^ ((R) & 7)) << 2) + ((J) & 3))

// Build B fragment (hi/lo bf16 split of E = exp(trans)) for k = kbase..kbase+7, col jc.
__device__ __forceinline__ void ldb(const float* __restrict__ trans, int kbase, int jc,
                                    bf16x8& BH, bf16x8& BL) {
#pragma unroll
    for (int e = 0; e < 8; ++e) {
        float v = expf(trans[(size_t)(kbase + e) * KK + jc]);
        unsigned short hb = f2bf(v);
        float hv = __uint_as_float(((unsigned)hb) << 16);
        BH[e] = (short)hb;
        BL[e] = (short)f2bf(v - hv);
    }
}

// ---------------- forward (denominator) kernel: 16 blocks x 512 threads ----------------
// Block handles NB=16 batches. Per step: P(16x128 bf16) x E(128x128 bf16 hi/lo) via
// 8 waves x [4 ds_read_b128 + 8 chained mfma_f32_16x16x32_bf16] -> 16x128 fp32,
// then X-multiply + exact pow2 renorm (from p_prev[r][0] bf16 exponent) + RNE pack.
// One lgkm-only barrier per step. Same math as the previous VALU kernel.
__global__ __launch_bounds__(NTHR, 1) void crf_fwd(
    const float* __restrict__ inputs,
    const float* __restrict__ trans,
    const int* __restrict__ mask,
    float* __restrict__ out)
{
    __shared__ __align__(16) unsigned short pbuf[2][NB * PSTR];
    __shared__ __align__(16) float ebuf[2][CHUNK * NB * KK];
    __shared__ float mbuf[2][CHUNK * NB];

    const int tid = threadIdx.x;
    const int l   = tid & 63;
    const int w   = tid >> 6;          // wave id 0..7 -> j-tile
    const int jc  = w * 16 + (l & 15); // output column (state j)
    const int kg  = l >> 4;            // 0..3
    const int r0  = kg * 4;            // C rows (batches) base for this lane
    const int b0  = blockIdx.x * NB;

    const int bb = tid >> 5;           // staging batch row 0..15
    const int kq = tid & 31;           // staging 16B granule
    const float* sbase = inputs + (size_t)(b0 + bb) * TT * KK + (size_t)kq * 4;
    const int xw = ((kq ^ (bb & 7)) << 2);   // swizzled granule offset (floats)

    // ---- B fragments: lane holds E[k = kt*32 + kg*8 + e][jc], hi+lo bf16 ----
    bf16x8 Bh0, Bh1, Bh2, Bh3, Bl0, Bl1, Bl2, Bl3;
    ldb(trans,  0 + kg * 8, jc, Bh0, Bl0);
    ldb(trans, 32 + kg * 8, jc, Bh1, Bl1);
    ldb(trans, 64 + kg * 8, jc, Bh2, Bl2);
    ldb(trans, 96 + kg * 8, jc, Bh3, Bl3);

    // ---- stage chunk 0 of X = exp(emissions), + mask ----
#pragma unroll
    for (int s = 0; s < CHUNK; ++s) {
        float4 e4 = *(const float4*)(sbase + (size_t)s * KK);
        e4.x = __expf(e4.x); e4.y = __expf(e4.y);
        e4.z = __expf(e4.z); e4.w = __expf(e4.w);
        *(float4*)&ebuf[0][(s * NB + bb) * KK + xw] = e4;
    }
    if (tid < CHUNK * NB) {
        int s = tid >> 4, bq = tid & 15;
        mbuf[0][s * NB + bq] = (float)mask[(size_t)(b0 + bq) * TT + s];
    }
    BARSYNC();

    // ---- t = 0: p = exp(alpha0) = X[0], m = 0 ----
    float pcur0, pcur1, pcur2, pcur3;
    int m0 = 0, m1 = 0, m2 = 0, m3 = 0;
    pcur0 = ebuf[0][XI(0, r0 + 0, jc)];
    pcur1 = ebuf[0][XI(0, r0 + 1, jc)];
    pcur2 = ebuf[0][XI(0, r0 + 2, jc)];
    pcur3 = ebuf[0][XI(0, r0 + 3, jc)];
    pbuf[0][(r0 + 0) * PSTR + jc] = f2bf(pcur0);
    pbuf[0][(r0 + 1) * PSTR + jc] = f2bf(pcur1);
    pbuf[0][(r0 + 2) * PSTR + jc] = f2bf(pcur2);
    pbuf[0][(r0 + 3) * PSTR + jc] = f2bf(pcur3);
    BARSYNC();

#define KSTEP(KT, BH, BL) { \
    union { uint4 q; bf16x8 v; } _a; \
    _a.q = *(const uint4*)(Pp + abase0 + (KT) * 32); \
    acch = __builtin_amdgcn_mfma_f32_16x16x32_bf16(_a.v, BH, acch, 0, 0, 0); \
    accl = __builtin_amdgcn_mfma_f32_16x16x32_bf16(_a.v, BL, accl, 0, 0, 0); }

#define EPI(I, PC, MI, UU) { \
    float z = acch[I] + accl[I]; \
    float X = eb[XI(s, r0 + I, jc)]; \
    float mi = mb[s * NB + r0 + I]; \
    int Ex = (int)((UU >> 7) & 255u) - 127; \
    float sc = __uint_as_float((unsigned)(127 - Ex) << 23); \
    float pn = (mi != 0.0f) ? z * X : PC; \
    PC = pn * sc; \
    MI += Ex; \
    Pn[(r0 + I) * PSTR + jc] = f2bf(PC); }

    const int abase0 = (l & 15) * PSTR + kg * 8;

    for (int c = 0; c < NCHUNK; ++c) {
        // prefetch next emission chunk into registers (raw; exp applied at store)
        float4 pf0, pf1, pf2, pf3; int mpre = 0;
        if (c + 1 < NCHUNK) {
            const float* pb_ = sbase + (size_t)(c + 1) * CHUNK * KK;
            pf0 = *(const float4*)(pb_ + 0 * KK);
            pf1 = *(const float4*)(pb_ + 1 * KK);
            pf2 = *(const float4*)(pb_ + 2 * KK);
            pf3 = *(const float4*)(pb_ + 3 * KK);
            if (tid < CHUNK * NB)
                mpre = mask[(size_t)(b0 + (tid & 15)) * TT + (c + 1) * CHUNK + (tid >> 4)];
        }
        const float* eb = ebuf[c & 1];
        const float* mb = mbuf[c & 1];
        for (int s = (c == 0) ? 1 : 0; s < CHUNK; ++s) {
            const int t = c * CHUNK + s;
            const unsigned short* Pp = pbuf[(t - 1) & 1];
            unsigned short* Pn = pbuf[t & 1];
            f32x4 acch = {0.f, 0.f, 0.f, 0.f};
            f32x4 accl = {0.f, 0.f, 0.f, 0.f};
            KSTEP(0, Bh0, Bl0) KSTEP(1, Bh1, Bl1)
            KSTEP(2, Bh2, Bl2) KSTEP(3, Bh3, Bl3)
            unsigned short u0 = Pp[(r0 + 0) * PSTR];
            unsigned short u1 = Pp[(r0 + 1) * PSTR];
            unsigned short u2 = Pp[(r0 + 2) * PSTR];
            unsigned short u3 = Pp[(r0 + 3) * PSTR];
            EPI(0, pcur0, m0, u0) EPI(1, pcur1, m1, u1)
            EPI(2, pcur2, m2, u2) EPI(3, pcur3, m3, u3)
            BARSYNC();
        }
        if (c + 1 < NCHUNK) {
            float* en = ebuf[(c + 1) & 1];
            pf0.x = __expf(pf0.x); pf0.y = __expf(pf0.y); pf0.z = __expf(pf0.z); pf0.w = __expf(pf0.w);
            pf1.x = __expf(pf1.x); pf1.y = __expf(pf1.y); pf1.z = __expf(pf1.z); pf1.w = __expf(pf1.w);
            pf2.x = __expf(pf2.x); pf2.y = __expf(pf2.y); pf2.z = __expf(pf2.z); pf2.w = __expf(pf2.w);
            pf3.x = __expf(pf3.x); pf3.y = __expf(pf3.y); pf3.z = __expf(pf3.z); pf3.w = __expf(pf3.w);
            *(float4*)&en[(0 * NB + bb) * KK + xw] = pf0;
            *(float4*)&en[(1 * NB + bb) * KK + xw] = pf1;
            *(float4*)&en[(2 * NB + bb) * KK + xw] = pf2;
            *(float4*)&en[(3 * NB + bb) * KK + xw] = pf3;
            if (tid < CHUNK * NB)
                mbuf[(c + 1) & 1][(tid >> 4) * NB + (tid & 15)] = (float)mpre;
            BARSYNC();
        }
    }

    // ---- denominator: per-batch LSE over j of (m*ln2 + log p) ----
    float* aw = ebuf[0];   // last chunk read ebuf[1]; ebuf[0] is free (16x128 fp32)
    aw[(r0 + 0) * KK + jc] = (float)m0 * 0.69314718055994531f + logf(pcur0);
    aw[(r0 + 1) * KK + jc] = (float)m1 * 0.69314718055994531f + logf(pcur1);
    aw[(r0 + 2) * KK + jc] = (float)m2 * 0.69314718055994531f + logf(pcur2);
    aw[(r0 + 3) * KK + jc] = (float)m3 * 0.69314718055994531f + logf(pcur3);
    BARSYNC();
    {
        int bq = tid >> 5, l32 = tid & 31;   // 32 lanes per batch, contiguous in a wave
        const float* ab = aw + bq * KK;
        float a0 = ab[l32 * 4 + 0], a1 = ab[l32 * 4 + 1];
        float a2 = ab[l32 * 4 + 2], a3 = ab[l32 * 4 + 3];
        float mx = fmaxf(fmaxf(a0, a1), fmaxf(a2, a3));
#pragma unroll
        for (int o = 1; o < 32; o <<= 1) mx = fmaxf(mx, __shfl_xor(mx, o));
        float ev = __expf(a0 - mx) + __expf(a1 - mx) + __expf(a2 - mx) + __expf(a3 - mx);
#pragma unroll
        for (int o = 1; o < 32; o <<= 1) ev += __shfl_xor(ev, o);
        if (l32 == 0) atomicAdd(out, -(mx + logf(ev)));
    }
}

// ---------------- numerator (gold-path) kernel: 256 blocks x 256 threads ----------------
__global__ __launch_bounds__(256, 1) void crf_num(
    const float* __restrict__ inputs,
    const float* __restrict__ trans,
    const int* __restrict__ tags,
    const int* __restrict__ mask,
    float* __restrict__ out)
{
    __shared__ float scratch[8];
    const int tid = threadIdx.x;
    const int b = blockIdx.x;
    const float* binp = inputs + (size_t)b * TT * KK;
    const int* bmask  = mask + (size_t)b * TT;
    const int* btags  = tags + (size_t)b * TT;
    float numpart = 0.0f, maskpart = 0.0f;
#pragma unroll
    for (int kk2 = 0; kk2 < TT / 256; ++kk2) {
        int t = tid + 256 * kk2;
        int tg = btags[t];
        float mf = (float)bmask[t];
        maskpart += mf;
        if (t < TT - 1) {
            int tg1   = btags[t + 1];
            float mf1 = (float)bmask[t + 1];
            numpart += trans[tg * KK + tg1] * mf1;
            numpart += binp[(size_t)t * KK + tg] * mf;
        }
    }
#pragma unroll
    for (int o = 1; o < 64; o <<= 1) numpart += __shfl_xor(numpart, o);
#pragma unroll
    for (int o = 1; o < 64; o <<= 1) maskpart += __shfl_xor(maskpart, o);
    if ((tid & 63) == 0) {
        scratch[tid >> 6]     = numpart;
        scratch[4 + (tid >> 6)] = maskpart;
    }
    __syncthreads();
    if (tid == 0) {
        float num  = (scratch[0] + scratch[1]) + (scratch[2] + scratch[3]);
        float msum = (scratch[4] + scratch[5]) + (scratch[6] + scratch[7]);
        int last_idx = (int)msum - 1;
        int ltag = btags[last_idx];
        num += binp[(size_t)(TT - 1) * KK + ltag] * (float)bmask[TT - 1];
        atomicAdd(out, num);
    }
}

extern "C" void kernel_launch(void* const* d_in, const int* in_sizes, int n_in,
                              void* d_out, int out_size, void* d_ws, size_t ws_size,
                              hipStream_t stream) {
    const float* inputs = (const float*)d_in[0];
    const float* trans  = (const float*)d_in[1];
    const int* tagsp    = (const int*)d_in[2];
    const int* maskp    = (const int*)d_in[3];
    float* out          = (float*)d_out;
    zero_out_kernel<<<1, 1, 0, stream>>>(out);
    crf_num<<<BB, 256, 0, stream>>>(inputs, trans, tagsp, maskp, out);
    crf_fwd<<<NBLK, NTHR, 0, stream>>>(inputs, trans, maskp, out);
}

// Round 4
// 743.032 us; speedup vs baseline: 1.1765x; 1.1765x over previous
//
#include <hip/hip_runtime.h>
#include <math.h>

#define BB 256
#define TT 1024
#define KK 128
#define NB 16                 // batches per forward block (MFMA M/N dim)
#define NBLK (BB / NB)        // 16 forward blocks
#define NTHR 512
#define CHUNK 4
#define NCHUNK (TT / CHUNK)   // 256
#define PSTR 136              // ushorts per P row (272 B)

typedef __attribute__((ext_vector_type(8))) short bf16x8;
typedef __attribute__((ext_vector_type(4))) float f32x4;

__global__ void zero_out_kernel(float* out) { out[0] = 0.0f; }

// RNE float -> bf16 bits
__device__ __forceinline__ unsigned short f2bf(float x) {
    unsigned b = __float_as_uint(x);
    return (unsigned short)((b + 0x7FFFu + ((b >> 16) & 1u)) >> 16);
}

// LGKM-only barrier: LDS is the only cross-wave dependency in the hot loop;
// global prefetch loads stay in flight across step barriers (never drain vmcnt).
#define BARSYNC() { asm volatile("s_waitcnt lgkmcnt(0)" ::: "memory"); \
                    __builtin_amdgcn_s_barrier(); \
                    asm volatile("" ::: "memory"); }

// Build E fragment (hi/lo bf16 split of E = exp(trans)) for k = kbase..kbase+7, col jc.
// Used as MFMA operand A: A[m=jc-in-tile][k] = E^T -> C rows become j.
__device__ __forceinline__ void ldb(const float* __restrict__ trans, int kbase, int jc,
                                    bf16x8& BH, bf16x8& BL) {
#pragma unroll
    for (int e = 0; e < 8; ++e) {
        float v = expf(trans[(size_t)(kbase + e) * KK + jc]);
        unsigned short hb = f2bf(v);
        float hv = __uint_as_float(((unsigned)hb) << 16);
        BH[e] = (short)hb;
        BL[e] = (short)f2bf(v - hv);
    }
}

// ---------------- forward (denominator) kernel: 16 blocks x 512 threads ----------------
// Z = E^T (A operand, registers) x P^T (B operand, LDS rows) so each lane's C
// fragment holds 4 CONSECUTIVE j of ONE batch r: epilogue is one float4 X read,
// 4 fmul+cndmask, 2 x v_cvt_pk_bf16_f32, one ds_write_b64. Renorm (exact pow2
// from bf16 P_prev[r][0] exponent) only every 4th step: bf16 precision is
// scale-free; 4-step worst-case growth (~g^5*spread ~ 1e29) stays in fp32 range.
__global__ __launch_bounds__(NTHR, 1) void crf_fwd(
    const float* __restrict__ inputs,
    const float* __restrict__ trans,
    const int* __restrict__ mask,
    float* __restrict__ out)
{
    __shared__ __align__(16) unsigned short pbuf[2][NB * PSTR];
    __shared__ __align__(16) float ebuf[2][CHUNK * NB * KK];
    __shared__ float mbuf[2][CHUNK * NB];

    const int tid = threadIdx.x;
    const int l   = tid & 63;
    const int w   = tid >> 6;          // wave id 0..7 -> j-tile
    const int r   = l & 15;            // C column = batch row
    const int kg  = l >> 4;            // k-group 0..3
    const int jc  = w * 16 + (l & 15); // E column for the A fragment
    const int j0  = w * 16 + kg * 4;   // C rows: lane owns j0..j0+3 of batch r
    const int b0  = blockIdx.x * NB;

    const int bb = tid >> 5;           // staging batch row 0..15
    const int kq = tid & 31;           // staging 16B granule 0..31
    const float* sbase = inputs + (size_t)(b0 + bb) * TT * KK + (size_t)kq * 4;
    const int xw = ((kq ^ bb) << 2);             // swizzled store granule (floats)
    const int xg = (((w * 4 + kg) ^ r) << 2);    // swizzled load granule for (r, j0)

    // ---- A fragments: lane holds E[k = kt*32 + kg*8 + e][jc], hi+lo bf16 ----
    bf16x8 Ah0, Ah1, Ah2, Ah3, Al0, Al1, Al2, Al3;
    ldb(trans,  0 + kg * 8, jc, Ah0, Al0);
    ldb(trans, 32 + kg * 8, jc, Ah1, Al1);
    ldb(trans, 64 + kg * 8, jc, Ah2, Al2);
    ldb(trans, 96 + kg * 8, jc, Ah3, Al3);

    // ---- stage chunk 0 of X = exp(emissions), + mask ----
#pragma unroll
    for (int s = 0; s < CHUNK; ++s) {
        float4 e4 = *(const float4*)(sbase + (size_t)s * KK);
        e4.x = __expf(e4.x); e4.y = __expf(e4.y);
        e4.z = __expf(e4.z); e4.w = __expf(e4.w);
        *(float4*)&ebuf[0][(s * NB + bb) * KK + xw] = e4;
    }
    if (tid < CHUNK * NB) {
        int s = tid >> 4, bq = tid & 15;
        mbuf[0][s * NB + bq] = (float)mask[(size_t)(b0 + bq) * TT + s];
    }
    BARSYNC();

    // ---- t = 0: p = exp(alpha0) = X[0], m = 0 ----
    float pcur0, pcur1, pcur2, pcur3;
    int m_int = 0;
    {
        float4 pc = *(const float4*)&ebuf[0][(0 * NB + r) * KK + xg];
        pcur0 = pc.x; pcur1 = pc.y; pcur2 = pc.z; pcur3 = pc.w;
        unsigned plo, phi;
        asm volatile("v_cvt_pk_bf16_f32 %0, %1, %2" : "=v"(plo) : "v"(pcur0), "v"(pcur1));
        asm volatile("v_cvt_pk_bf16_f32 %0, %1, %2" : "=v"(phi) : "v"(pcur2), "v"(pcur3));
        *(uint2*)&pbuf[0][r * PSTR + j0] = make_uint2(plo, phi);
    }
    BARSYNC();

// One recursion step. S = step-in-chunk (compile-time), RN = renorm this step.
// Pp parity = (c*4+S-1)&1 = (S-1)&1 ; Pn parity = S&1 (CHUNK=4 even).
#define STEP(S, RN) { \
    const unsigned short* Pp = pbuf[((S) + 1) & 1]; \
    unsigned short* Pn = pbuf[(S) & 1]; \
    float4 xv = *(const float4*)&eb[((S) * NB + r) * KK + xg]; \
    float mi = mb[(S) * NB + r]; \
    const unsigned short* pr = Pp + r * PSTR + kg * 8; \
    union { uint4 q; bf16x8 v; } a0, a1, a2, a3; \
    a0.q = *(const uint4*)(pr); \
    a1.q = *(const uint4*)(pr + 32); \
    a2.q = *(const uint4*)(pr + 64); \
    a3.q = *(const uint4*)(pr + 96); \
    f32x4 acch = {0.f, 0.f, 0.f, 0.f}; \
    f32x4 accl = {0.f, 0.f, 0.f, 0.f}; \
    acch = __builtin_amdgcn_mfma_f32_16x16x32_bf16(Ah0, a0.v, acch, 0, 0, 0); \
    accl = __builtin_amdgcn_mfma_f32_16x16x32_bf16(Al0, a0.v, accl, 0, 0, 0); \
    acch = __builtin_amdgcn_mfma_f32_16x16x32_bf16(Ah1, a1.v, acch, 0, 0, 0); \
    accl = __builtin_amdgcn_mfma_f32_16x16x32_bf16(Al1, a1.v, accl, 0, 0, 0); \
    acch = __builtin_amdgcn_mfma_f32_16x16x32_bf16(Ah2, a2.v, acch, 0, 0, 0); \
    accl = __builtin_amdgcn_mfma_f32_16x16x32_bf16(Al2, a2.v, accl, 0, 0, 0); \
    acch = __builtin_amdgcn_mfma_f32_16x16x32_bf16(Ah3, a3.v, acch, 0, 0, 0); \
    accl = __builtin_amdgcn_mfma_f32_16x16x32_bf16(Al3, a3.v, accl, 0, 0, 0); \
    float pn0 = (mi != 0.0f) ? (acch[0] + accl[0]) * xv.x : pcur0; \
    float pn1 = (mi != 0.0f) ? (acch[1] + accl[1]) * xv.y : pcur1; \
    float pn2 = (mi != 0.0f) ? (acch[2] + accl[2]) * xv.z : pcur2; \
    float pn3 = (mi != 0.0f) ? (acch[3] + accl[3]) * xv.w : pcur3; \
    if (RN) { \
        unsigned short u = Pp[r * PSTR]; \
        int Ex = (int)((u >> 7) & 255u) - 127; \
        float sc = __uint_as_float((unsigned)(127 - Ex) << 23); \
        pn0 *= sc; pn1 *= sc; pn2 *= sc; pn3 *= sc; \
        m_int += Ex; \
    } \
    pcur0 = pn0; pcur1 = pn1; pcur2 = pn2; pcur3 = pn3; \
    unsigned plo, phi; \
    asm volatile("v_cvt_pk_bf16_f32 %0, %1, %2" : "=v"(plo) : "v"(pn0), "v"(pn1)); \
    asm volatile("v_cvt_pk_bf16_f32 %0, %1, %2" : "=v"(phi) : "v"(pn2), "v"(pn3)); \
    *(uint2*)&Pn[r * PSTR + j0] = make_uint2(plo, phi); \
    BARSYNC(); }

    for (int c = 0; c < NCHUNK; ++c) {
        // prefetch next emission chunk into registers (raw; exp applied at store)
        float4 pf0, pf1, pf2, pf3; int mpre = 0;
        if (c + 1 < NCHUNK) {
            const float* pb_ = sbase + (size_t)(c + 1) * CHUNK * KK;
            pf0 = *(const float4*)(pb_ + 0 * KK);
            pf1 = *(const float4*)(pb_ + 1 * KK);
            pf2 = *(const float4*)(pb_ + 2 * KK);
            pf3 = *(const float4*)(pb_ + 3 * KK);
            if (tid < CHUNK * NB)
                mpre = mask[(size_t)(b0 + (tid & 15)) * TT + (c + 1) * CHUNK + (tid >> 4)];
        }
        const float* eb = ebuf[c & 1];
        const float* mb = mbuf[c & 1];
        if (c == 0) {
            STEP(1, 0) STEP(2, 0) STEP(3, 1)
        } else {
            STEP(0, 0) STEP(1, 0) STEP(2, 0) STEP(3, 1)
        }
        if (c + 1 < NCHUNK) {
            float* en = ebuf[(c + 1) & 1];
            pf0.x = __expf(pf0.x); pf0.y = __expf(pf0.y); pf0.z = __expf(pf0.z); pf0.w = __expf(pf0.w);
            pf1.x = __expf(pf1.x); pf1.y = __expf(pf1.y); pf1.z = __expf(pf1.z); pf1.w = __expf(pf1.w);
            pf2.x = __expf(pf2.x); pf2.y = __expf(pf2.y); pf2.z = __expf(pf2.z); pf2.w = __expf(pf2.w);
            pf3.x = __expf(pf3.x); pf3.y = __expf(pf3.y); pf3.z = __expf(pf3.z); pf3.w = __expf(pf3.w);
            *(float4*)&en[(0 * NB + bb) * KK + xw] = pf0;
            *(float4*)&en[(1 * NB + bb) * KK + xw] = pf1;
            *(float4*)&en[(2 * NB + bb) * KK + xw] = pf2;
            *(float4*)&en[(3 * NB + bb) * KK + xw] = pf3;
            if (tid < CHUNK * NB)
                mbuf[(c + 1) & 1][(tid >> 4) * NB + (tid & 15)] = (float)mpre;
            BARSYNC();
        }
    }
#undef STEP

    // ---- denominator: per-batch LSE over j of (m*ln2 + log p) ----
    // Last chunk read ebuf[1]; ebuf[0] is free (16 x 128 fp32, plain layout).
    float* aw = ebuf[0];
    {
        const float c2 = 0.69314718055994531f;
        float4 av;
        av.x = (float)m_int * c2 + logf(pcur0);
        av.y = (float)m_int * c2 + logf(pcur1);
        av.z = (float)m_int * c2 + logf(pcur2);
        av.w = (float)m_int * c2 + logf(pcur3);
        *(float4*)&aw[r * KK + j0] = av;
    }
    BARSYNC();
    {
        int bq = tid >> 5, l32 = tid & 31;   // 32 lanes per batch, within one wave-half
        const float* ab = aw + bq * KK;
        float4 av = *(const float4*)&ab[l32 * 4];
        float mx = fmaxf(fmaxf(av.x, av.y), fmaxf(av.z, av.w));
#pragma unroll
        for (int o = 1; o < 32; o <<= 1) mx = fmaxf(mx, __shfl_xor(mx, o));
        float ev = __expf(av.x - mx) + __expf(av.y - mx) + __expf(av.z - mx) + __expf(av.w - mx);
#pragma unroll
        for (int o = 1; o < 32; o <<= 1) ev += __shfl_xor(ev, o);
        if (l32 == 0) atomicAdd(out, -(mx + logf(ev)));
    }
}

// ---------------- numerator (gold-path) kernel: 256 blocks x 256 threads ----------------
__global__ __launch_bounds__(256, 1) void crf_num(
    const float* __restrict__ inputs,
    const float* __restrict__ trans,
    const int* __restrict__ tags,
    const int* __restrict__ mask,
    float* __restrict__ out)
{
    __shared__ float scratch[8];
    const int tid = threadIdx.x;
    const int b = blockIdx.x;
    const float* binp = inputs + (size_t)b * TT * KK;
    const int* bmask  = mask + (size_t)b * TT;
    const int* btags  = tags + (size_t)b * TT;
    float numpart = 0.0f, maskpart = 0.0f;
#pragma unroll
    for (int kk2 = 0; kk2 < TT / 256; ++kk2) {
        int t = tid + 256 * kk2;
        int tg = btags[t];
        float mf = (float)bmask[t];
        maskpart += mf;
        if (t < TT - 1) {
            int tg1   = btags[t + 1];
            float mf1 = (float)bmask[t + 1];
            numpart += trans[tg * KK + tg1] * mf1;
            numpart += binp[(size_t)t * KK + tg] * mf;
        }
    }
#pragma unroll
    for (int o = 1; o < 64; o <<= 1) numpart += __shfl_xor(numpart, o);
#pragma unroll
    for (int o = 1; o < 64; o <<= 1) maskpart += __shfl_xor(maskpart, o);
    if ((tid & 63) == 0) {
        scratch[tid >> 6]     = numpart;
        scratch[4 + (tid >> 6)] = maskpart;
    }
    __syncthreads();
    if (tid == 0) {
        float num  = (scratch[0] + scratch[1]) + (scratch[2] + scratch[3]);
        float msum = (scratch[4] + scratch[5]) + (scratch[6] + scratch[7]);
        int last_idx = (int)msum - 1;
        int ltag = btags[last_idx];
        num += binp[(size_t)(TT - 1) * KK + ltag] * (float)bmask[TT - 1];
        atomicAdd(out, num);
    }
}

extern "C" void kernel_launch(void* const* d_in, const int* in_sizes, int n_in,
                              void* d_out, int out_size, void* d_ws, size_t ws_size,
                              hipStream_t stream) {
    const float* inputs = (const float*)d_in[0];
    const float* trans  = (const float*)d_in[1];
    const int* tagsp    = (const int*)d_in[2];
    const int* maskp    = (const int*)d_in[3];
    float* out          = (float*)d_out;
    zero_out_kernel<<<1, 1, 0, stream>>>(out);
    crf_num<<<BB, 256, 0, stream>>>(inputs, trans, tagsp, maskp, out);
    crf_fwd<<<NBLK, NTHR, 0, stream>>>(inputs, trans, maskp, out);
}